// Round 4
// baseline (439.085 us; speedup 1.0000x reference)
//
#include <hip/hip_runtime.h>

// SlidingKernelAttention: unfold(k=4,s=1) -> per-(b,c,patch-offset) attention
// over seq=256 tokens of dim=16 -> overlap-add fold.
// B=2, C=64, H=W=67, Ho=Wo=64, N = B*C*16 = 2048 independent sequences.
//
// R4: full-MFMA pass 1. The 16x16 MFMA C/D layout (lane=col+16*(row>>2),
// reg=row&3) coincides with both A- and B-operand layouts (lane=idx+16*(k>>2),
// reg=k&3), so:
//   K^T = Wk.X^T      -> C-result IS the A-fragment of K      (for S^T=K.Q^T)
//   V   = X.Wv^T      -> C-result IS the A-fragment of V^T    (for O^T=V^T.P^T)
//   Q^T = s.Wq.X^T    -> C-result IS the B-fragment of Q^T
//   P^T = exp(S^T)    -> C-result IS the B-fragment of P^T    (R3 trick)
// Each wave computes all 16 K/V fragments in REGISTERS (36 projection MFMAs);
// the 256-key main loop reads no LDS at all. LDS holds only the f16 X-tile
// fragments (8 KB) + w (3 KB); one __syncthreads total.
// ao workspace stored f16 to halve pass-2 traffic.

#define BATCH 2
#define CHAN 64
#define HWDIM 67
#define SEQ 256
#define DIM 16
#define NSEQ 2048            // BATCH*CHAN*16
#define PLANE 4096           // 64*64 elems per sequence
#define OUT_TOTAL (BATCH * CHAN * HWDIM * HWDIM)   // 574592
#define ATT_SCALE 0.70710678118654752f             // (DIM/HEADS)^-0.5
#define LOG2E 1.44269504088896340736f

typedef _Float16 half4 __attribute__((ext_vector_type(4)));
typedef float float4v __attribute__((ext_vector_type(4)));

static __device__ __forceinline__ half4 pack4(float4v c) {
    half4 h;
    h[0] = (_Float16)c[0]; h[1] = (_Float16)c[1];
    h[2] = (_Float16)c[2]; h[3] = (_Float16)c[3];
    return h;
}

__global__ __launch_bounds__(256) void ska_attn_pass1(
    const float* __restrict__ x,      // [B, C, 67, 67]
    const float* __restrict__ w,      // [48, 16]
    _Float16* __restrict__ ao)        // [NSEQ, 64, 64] workspace (f16)
{
    __shared__ float sw[3 * DIM * DIM];       // 48x16 f32 = 3 KB
    __shared__ _Float16 xF[16][64][4];        // X-tile frags: X[tok][d] at
                                              // [tile][ (tok&15)+16*(d>>2) ][ d&3 ]  (8 KB)

    const int n  = blockIdx.x;
    const int p  = n & 15;
    const int bc = n >> 4;
    const int oi = p >> 2;
    const int oj = p & 3;

    const int s   = threadIdx.x;          // token id 0..255
    const int ph  = s >> 2;
    const int pw0 = (s & 3) * DIM;

    // stage w (f32) into LDS
#pragma unroll
    for (int r = 0; r < 3; ++r)
        sw[r * 256 + s] = w[r * 256 + s];

    // load this token's 16 features; stage as f16 X-fragment
    const float* xrow = x + ((size_t)bc * HWDIM + (ph + oi)) * HWDIM + pw0 + oj;
    const int kt = s >> 4, kk = s & 15;
#pragma unroll
    for (int dh = 0; dh < 4; ++dh) {
        half4 h;
#pragma unroll
        for (int r = 0; r < 4; ++r) h[r] = (_Float16)xrow[4 * dh + r];
        *(half4*)&xF[kt][kk + 16 * dh][0] = h;
    }

    __syncthreads();   // sw + xF ready (the only barrier)

    const int wave = threadIdx.x >> 6;
    const int lane = threadIdx.x & 63;
    const int o = lane & 15;      // weight output row held by this lane
    const int g = lane >> 4;      // k-group

    // W fragments (A[m=o][k=d] at lane o+16*(d>>2), reg d&3); also valid as
    // B[k=d][n=o]. One-time gather from LDS.
    half4 wqf, wkf, wvf;
#pragma unroll
    for (int r = 0; r < 4; ++r) {
        const int d = 4 * g + r;
        wqf[r] = (_Float16)(sw[(0 * DIM + o) * DIM + d] * (ATT_SCALE * LOG2E));
        wkf[r] = (_Float16)sw[(1 * DIM + o) * DIM + d];
        wvf[r] = (_Float16)sw[(2 * DIM + o) * DIM + d];
    }

    const float4v zf = (float4v){0.f, 0.f, 0.f, 0.f};

    // projection: all 16 K- and V-fragments into registers
    half4 kfr[16], vfr[16];
#pragma unroll
    for (int t = 0; t < 16; ++t) {
        const half4 xf = *(const half4*)&xF[t][lane][0];
        // K^T = Wk . X^T  -> A-frag of K
        kfr[t] = pack4(__builtin_amdgcn_mfma_f32_16x16x16f16(wkf, xf, zf, 0, 0, 0));
        // V = X . Wv^T    -> A-frag of V^T
        vfr[t] = pack4(__builtin_amdgcn_mfma_f32_16x16x16f16(xf, wvf, zf, 0, 0, 0));
    }
    // this wave's 4 Q^T B-fragments (scale*log2e folded into wq)
    half4 qfr[4];
#pragma unroll
    for (int j = 0; j < 4; ++j) {
        const half4 xf = *(const half4*)&xF[4 * wave + j][lane][0];
        qfr[j] = pack4(__builtin_amdgcn_mfma_f32_16x16x16f16(wqf, xf, zf, 0, 0, 0));
    }

    float4v oacc[4];
    float lpart[4];
#pragma unroll
    for (int j = 0; j < 4; ++j) {
        oacc[j] = zf;
        lpart[j] = 0.f;
    }

    // main loop: pure register MFMA + exp
    for (int t = 0; t < 16; ++t) {
#pragma unroll
        for (int j = 0; j < 4; ++j) {
            float4v sfr = __builtin_amdgcn_mfma_f32_16x16x16f16(kfr[t], qfr[j], zf, 0, 0, 0);
            float p0 = __builtin_amdgcn_exp2f(sfr[0]);
            float p1 = __builtin_amdgcn_exp2f(sfr[1]);
            float p2 = __builtin_amdgcn_exp2f(sfr[2]);
            float p3 = __builtin_amdgcn_exp2f(sfr[3]);
            lpart[j] += (p0 + p1) + (p2 + p3);
            half4 pb;
            pb[0] = (_Float16)p0; pb[1] = (_Float16)p1;
            pb[2] = (_Float16)p2; pb[3] = (_Float16)p3;
            oacc[j] = __builtin_amdgcn_mfma_f32_16x16x16f16(vfr[t], pb, oacc[j], 0, 0, 0);
        }
    }

    // softmax denom: sum lane groups {qq, qq+16, qq+32, qq+48}
#pragma unroll
    for (int j = 0; j < 4; ++j) {
        float lj = lpart[j];
        lj += __shfl_xor(lj, 16, 64);
        lj += __shfl_xor(lj, 32, 64);
        const float rl = 1.f / lj;
        const int query = (4 * wave + j) * 16 + (lane & 15);
        half4 hv;
        hv[0] = (_Float16)(oacc[j][0] * rl);
        hv[1] = (_Float16)(oacc[j][1] * rl);
        hv[2] = (_Float16)(oacc[j][2] * rl);
        hv[3] = (_Float16)(oacc[j][3] * rl);
        *(half4*)(ao + (size_t)n * PLANE + query * DIM + 4 * g) = hv;
    }
}

__global__ __launch_bounds__(256) void ska_fold_pass2(
    const _Float16* __restrict__ ao,  // [NSEQ, 64, 64] f16
    float* __restrict__ out)          // [B, C, 67, 67]
{
    const int idx = blockIdx.x * 256 + threadIdx.x;
    if (idx >= OUT_TOTAL) return;
    const int w  = idx % HWDIM;
    const int t  = idx / HWDIM;
    const int h  = t % HWDIM;
    const int bc = t / HWDIM;

    const _Float16* base = ao + (size_t)bc * 16 * PLANE;
    float acc = 0.f;
#pragma unroll
    for (int i = 0; i < 4; ++i) {
        const int ph = h - i;
        if (ph < 0 || ph >= 64) continue;
#pragma unroll
        for (int j = 0; j < 4; ++j) {
            const int pw = w - j;
            if (pw < 0 || pw >= 64) continue;
            acc += (float)base[(i * 4 + j) * PLANE + ph * 64 + pw];
        }
    }
    out[idx] = acc;
}

// ---- fallback (atomic fold) if workspace is too small ----
__global__ __launch_bounds__(256) void ska_attn_atomic(
    const float* __restrict__ x, const float* __restrict__ w,
    float* __restrict__ out)
{
    __shared__ float sw[3 * DIM * DIM];
    __shared__ float sk[SEQ][DIM];
    __shared__ float sv[SEQ][DIM];

    const int n = blockIdx.x, p = n & 15, bc = n >> 4, oi = p >> 2, oj = p & 3;
    const int s = threadIdx.x, ph = s >> 2, pw0 = (s & 3) * DIM;

#pragma unroll
    for (int r = 0; r < 3; ++r) sw[r * 256 + s] = w[r * 256 + s];

    const float* xrow = x + ((size_t)bc * HWDIM + (ph + oi)) * HWDIM + pw0 + oj;
    float xr[DIM];
#pragma unroll
    for (int d = 0; d < DIM; ++d) xr[d] = xrow[d];
    __syncthreads();

    float q[DIM];
#pragma unroll
    for (int o = 0; o < DIM; ++o) {
        float aq = 0.f, ak = 0.f, av = 0.f;
#pragma unroll
        for (int d = 0; d < DIM; ++d) {
            aq += xr[d] * sw[o * DIM + d];
            ak += xr[d] * sw[(DIM + o) * DIM + d];
            av += xr[d] * sw[(2 * DIM + o) * DIM + d];
        }
        q[o] = aq * ATT_SCALE; sk[s][o] = ak; sv[s][o] = av;
    }
    __syncthreads();

    float l = 0.f, acc[DIM];
#pragma unroll
    for (int d = 0; d < DIM; ++d) acc[d] = 0.f;
    for (int t = 0; t < SEQ; ++t) {
        float sc = 0.f;
#pragma unroll
        for (int d = 0; d < DIM; ++d) sc += q[d] * sk[t][d];
        const float pe = __expf(sc);
        l += pe;
#pragma unroll
        for (int d = 0; d < DIM; ++d) acc[d] += pe * sv[t][d];
    }
    const float rl = 1.f / l;
    float* obase = out + ((size_t)bc * HWDIM + (ph + oi)) * HWDIM + pw0 + oj;
#pragma unroll
    for (int d = 0; d < DIM; ++d) atomicAdd(&obase[d], acc[d] * rl);
}

extern "C" void kernel_launch(void* const* d_in, const int* in_sizes, int n_in,
                              void* d_out, int out_size, void* d_ws, size_t ws_size,
                              hipStream_t stream) {
    const float* x = (const float*)d_in[0];
    const float* w = (const float*)d_in[1];
    float* out = (float*)d_out;

    const size_t need = (size_t)NSEQ * PLANE * sizeof(_Float16);   // 16.8 MB
    if (ws_size >= need) {
        _Float16* ao = (_Float16*)d_ws;
        ska_attn_pass1<<<NSEQ, 256, 0, stream>>>(x, w, ao);
        ska_fold_pass2<<<(OUT_TOTAL + 255) / 256, 256, 0, stream>>>(ao, out);
    } else {
        hipMemsetAsync(out, 0, (size_t)out_size * sizeof(float), stream);
        ska_attn_atomic<<<NSEQ, 256, 0, stream>>>(x, w, out);
    }
}

// Round 6
// 92.769 us; speedup vs baseline: 4.7331x; 4.7331x over previous
//
#include <hip/hip_runtime.h>

// SlidingKernelAttention: unfold(k=4,s=1) -> per-(b,c,patch-offset) attention
// over seq=256 tokens of dim=16 -> overlap-add fold.
// B=2, C=64, H=W=67, Ho=Wo=64, N = B*C*16 = 2048 independent sequences.
//
// R6 = R5 with compile fix (scalar _Float16 casts instead of cvt_pkrtz, whose
// __fp16-vector return type clashes with _Float16 ext-vectors).
// R5 design: MFMA everything, all fragments STATICALLY indexed (R4's
// regression was dynamic register-array indexing -> scratch lowering).
// Layout identity: 16x16 MFMA C/D layout (lane=col+16*(row>>2), reg=row&3)
// == A-operand layout == B-operand layout, so projection MFMA results ARE
// the attention MFMA operands:
//   K^T = Wk.X^T       -> A-frag of K      (for S^T = K.Q^T)
//   V   = X.Wv^T       -> A-frag of V^T    (for O^T = V^T.P^T)
//   Q^T = s.Wq.X^T     -> B-frag of Q^T
//   P^T = exp2(S^T)    -> B-frag of P^T    (in-register)
// K/V frags in LDS interleaved 16B/lane -> ONE ds_read_b128 per k-tile.
// xF staging is wave-private -> single __syncthreads total.
// w read per-lane from global (3 KB, L1-broadcast). ao stored f16.

#define BATCH 2
#define CHAN 64
#define HWDIM 67
#define SEQ 256
#define DIM 16
#define NSEQ 2048            // BATCH*CHAN*16
#define PLANE 4096           // 64*64 elems per sequence
#define OUT_TOTAL (BATCH * CHAN * HWDIM * HWDIM)   // 574592
#define ATT_SCALE 0.70710678118654752f             // (DIM/HEADS)^-0.5
#define LOG2E 1.44269504088896340736f

typedef _Float16 half4 __attribute__((ext_vector_type(4)));
typedef _Float16 half8 __attribute__((ext_vector_type(8)));
typedef float float4v __attribute__((ext_vector_type(4)));

static __device__ __forceinline__ half4 pack4(float4v c) {
    half4 h;
    h[0] = (_Float16)c[0]; h[1] = (_Float16)c[1];
    h[2] = (_Float16)c[2]; h[3] = (_Float16)c[3];
    return h;
}

__global__ __launch_bounds__(256, 4) void ska_attn_pass1(
    const float* __restrict__ x,      // [B, C, 67, 67]
    const float* __restrict__ w,      // [48, 16]
    _Float16* __restrict__ ao)        // [NSEQ, 64, 64] workspace (f16)
{
    __shared__ _Float16 xF[16][64][4];     // X-tile frags (wave-private), 8 KB
    __shared__ _Float16 kvA[16][64][8];    // [0:4]=K A-frag, [4:8]=V^T A-frag, 16 KB

    const int n  = blockIdx.x;
    const int p  = n & 15;
    const int bc = n >> 4;
    const int oi = p >> 2;
    const int oj = p & 3;

    const int s   = threadIdx.x;          // token id 0..255
    const int ph  = s >> 2;
    const int pw0 = (s & 3) * DIM;

    // stage this token's 16 features as f16 X-fragment (wave-private tiles)
    const float* xrow = x + ((size_t)bc * HWDIM + (ph + oi)) * HWDIM + pw0 + oj;
    const int kt = s >> 4, kk = s & 15;
#pragma unroll
    for (int dh = 0; dh < 4; ++dh) {
        half4 h;
#pragma unroll
        for (int r = 0; r < 4; ++r) h[r] = (_Float16)xrow[4 * dh + r];
        *(half4*)&xF[kt][kk + 16 * dh][0] = h;
    }

    const int wave = s >> 6;
    const int lane = s & 63;
    const int o = lane & 15;      // weight output row held by this lane
    const int g = lane >> 4;      // k-group

    // weight fragments straight from global (3 KB, L1-resident)
    const float4 wq4 = *(const float4*)(w + ( 0 + o) * DIM + 4 * g);
    const float4 wk4 = *(const float4*)(w + (16 + o) * DIM + 4 * g);
    const float4 wv4 = *(const float4*)(w + (32 + o) * DIM + 4 * g);
    half4 wqf, wkf, wvf;
    wqf[0] = (_Float16)(wq4.x * (ATT_SCALE * LOG2E));
    wqf[1] = (_Float16)(wq4.y * (ATT_SCALE * LOG2E));
    wqf[2] = (_Float16)(wq4.z * (ATT_SCALE * LOG2E));
    wqf[3] = (_Float16)(wq4.w * (ATT_SCALE * LOG2E));
    wkf[0] = (_Float16)wk4.x; wkf[1] = (_Float16)wk4.y;
    wkf[2] = (_Float16)wk4.z; wkf[3] = (_Float16)wk4.w;
    wvf[0] = (_Float16)wv4.x; wvf[1] = (_Float16)wv4.y;
    wvf[2] = (_Float16)wv4.z; wvf[3] = (_Float16)wv4.w;

    const float4v zf = (float4v){0.f, 0.f, 0.f, 0.f};

    // projection: wave w handles tiles 4w..4w+3 (the tiles it staged in xF —
    // same-wave LDS ordering, no barrier needed before reading xF).
    half4 qfr[4];
#pragma unroll
    for (int u = 0; u < 4; ++u) {
        const int t = 4 * wave + u;
        const half4 xf = *(const half4*)&xF[t][lane][0];
        const half4 kf = pack4(__builtin_amdgcn_mfma_f32_16x16x16f16(wkf, xf, zf, 0, 0, 0));
        const half4 vf = pack4(__builtin_amdgcn_mfma_f32_16x16x16f16(xf, wvf, zf, 0, 0, 0));
        half8 kv;
        kv[0] = kf[0]; kv[1] = kf[1]; kv[2] = kf[2]; kv[3] = kf[3];
        kv[4] = vf[0]; kv[5] = vf[1]; kv[6] = vf[2]; kv[7] = vf[3];
        *(half8*)&kvA[t][lane][0] = kv;
        qfr[u] = pack4(__builtin_amdgcn_mfma_f32_16x16x16f16(wqf, xf, zf, 0, 0, 0));
    }
    __syncthreads();   // kvA ready (the only barrier)

    float4v oacc[4];
    float lpart[4];
#pragma unroll
    for (int j = 0; j < 4; ++j) {
        oacc[j] = zf;
        lpart[j] = 0.f;
    }

    // main loop: one ds_read_b128 per k-tile, rest pure register MFMA + exp2
#pragma unroll 4
    for (int t = 0; t < 16; ++t) {
        const half8 kv = *(const half8*)&kvA[t][lane][0];
        half4 kf, vf;
        kf[0] = kv[0]; kf[1] = kv[1]; kf[2] = kv[2]; kf[3] = kv[3];
        vf[0] = kv[4]; vf[1] = kv[5]; vf[2] = kv[6]; vf[3] = kv[7];
#pragma unroll
        for (int j = 0; j < 4; ++j) {
            float4v sfr = __builtin_amdgcn_mfma_f32_16x16x16f16(kf, qfr[j], zf, 0, 0, 0);
            const float p0 = __builtin_amdgcn_exp2f(sfr[0]);
            const float p1 = __builtin_amdgcn_exp2f(sfr[1]);
            const float p2 = __builtin_amdgcn_exp2f(sfr[2]);
            const float p3 = __builtin_amdgcn_exp2f(sfr[3]);
            lpart[j] += (p0 + p1) + (p2 + p3);
            half4 pb;
            pb[0] = (_Float16)p0; pb[1] = (_Float16)p1;
            pb[2] = (_Float16)p2; pb[3] = (_Float16)p3;
            oacc[j] = __builtin_amdgcn_mfma_f32_16x16x16f16(vf, pb, oacc[j], 0, 0, 0);
        }
    }

    // softmax denom: sum lane groups {qq, qq+16, qq+32, qq+48}; store O^T frag
#pragma unroll
    for (int j = 0; j < 4; ++j) {
        float lj = lpart[j];
        lj += __shfl_xor(lj, 16, 64);
        lj += __shfl_xor(lj, 32, 64);
        const float rl = 1.f / lj;
        const int query = (4 * wave + j) * 16 + (lane & 15);
        half4 hv;
        hv[0] = (_Float16)(oacc[j][0] * rl);
        hv[1] = (_Float16)(oacc[j][1] * rl);
        hv[2] = (_Float16)(oacc[j][2] * rl);
        hv[3] = (_Float16)(oacc[j][3] * rl);
        *(half4*)(ao + (size_t)n * PLANE + query * DIM + 4 * g) = hv;
    }
}

__global__ __launch_bounds__(256) void ska_fold_pass2(
    const _Float16* __restrict__ ao,  // [NSEQ, 64, 64] f16
    float* __restrict__ out)          // [B, C, 67, 67]
{
    const int idx = blockIdx.x * 256 + threadIdx.x;
    if (idx >= OUT_TOTAL) return;
    const int w  = idx % HWDIM;
    const int t  = idx / HWDIM;
    const int h  = t % HWDIM;
    const int bc = t / HWDIM;

    const _Float16* base = ao + (size_t)bc * 16 * PLANE;
    float acc = 0.f;
#pragma unroll
    for (int i = 0; i < 4; ++i) {
        const int ph = h - i;
        if (ph < 0 || ph >= 64) continue;
#pragma unroll
        for (int j = 0; j < 4; ++j) {
            const int pw = w - j;
            if (pw < 0 || pw >= 64) continue;
            acc += (float)base[(i * 4 + j) * PLANE + ph * 64 + pw];
        }
    }
    out[idx] = acc;
}

// ---- fallback (atomic fold) if workspace is too small ----
__global__ __launch_bounds__(256) void ska_attn_atomic(
    const float* __restrict__ x, const float* __restrict__ w,
    float* __restrict__ out)
{
    __shared__ float sw[3 * DIM * DIM];
    __shared__ float sk[SEQ][DIM];
    __shared__ float sv[SEQ][DIM];

    const int n = blockIdx.x, p = n & 15, bc = n >> 4, oi = p >> 2, oj = p & 3;
    const int s = threadIdx.x, ph = s >> 2, pw0 = (s & 3) * DIM;

#pragma unroll
    for (int r = 0; r < 3; ++r) sw[r * 256 + s] = w[r * 256 + s];

    const float* xrow = x + ((size_t)bc * HWDIM + (ph + oi)) * HWDIM + pw0 + oj;
    float xr[DIM];
#pragma unroll
    for (int d = 0; d < DIM; ++d) xr[d] = xrow[d];
    __syncthreads();

    float q[DIM];
#pragma unroll
    for (int o = 0; o < DIM; ++o) {
        float aq = 0.f, ak = 0.f, av = 0.f;
#pragma unroll
        for (int d = 0; d < DIM; ++d) {
            aq += xr[d] * sw[o * DIM + d];
            ak += xr[d] * sw[(DIM + o) * DIM + d];
            av += xr[d] * sw[(2 * DIM + o) * DIM + d];
        }
        q[o] = aq * ATT_SCALE; sk[s][o] = ak; sv[s][o] = av;
    }
    __syncthreads();

    float l = 0.f, acc[DIM];
#pragma unroll
    for (int d = 0; d < DIM; ++d) acc[d] = 0.f;
    for (int t = 0; t < SEQ; ++t) {
        float sc = 0.f;
#pragma unroll
        for (int d = 0; d < DIM; ++d) sc += q[d] * sk[t][d];
        const float pe = __expf(sc);
        l += pe;
#pragma unroll
        for (int d = 0; d < DIM; ++d) acc[d] += pe * sv[t][d];
    }
    const float rl = 1.f / l;
    float* obase = out + ((size_t)bc * HWDIM + (ph + oi)) * HWDIM + pw0 + oj;
#pragma unroll
    for (int d = 0; d < DIM; ++d) atomicAdd(&obase[d], acc[d] * rl);
}

extern "C" void kernel_launch(void* const* d_in, const int* in_sizes, int n_in,
                              void* d_out, int out_size, void* d_ws, size_t ws_size,
                              hipStream_t stream) {
    const float* x = (const float*)d_in[0];
    const float* w = (const float*)d_in[1];
    float* out = (float*)d_out;

    const size_t need = (size_t)NSEQ * PLANE * sizeof(_Float16);   // 16.8 MB
    if (ws_size >= need) {
        _Float16* ao = (_Float16*)d_ws;
        ska_attn_pass1<<<NSEQ, 256, 0, stream>>>(x, w, ao);
        ska_fold_pass2<<<(OUT_TOTAL + 255) / 256, 256, 0, stream>>>(ao, out);
    } else {
        (void)hipMemsetAsync(out, 0, (size_t)out_size * sizeof(float), stream);
        ska_attn_atomic<<<NSEQ, 256, 0, stream>>>(x, w, out);
    }
}

// Round 7
// 88.859 us; speedup vs baseline: 4.9414x; 1.0440x over previous
//
#include <hip/hip_runtime.h>

// SlidingKernelAttention: unfold(k=4,s=1) -> per-(b,c,patch-offset) attention
// over seq=256 tokens of dim=16 -> overlap-add fold.
// B=2, C=64, H=W=67, Ho=Wo=64, N = B*C*16 = 2048 independent sequences.
//
// R7 = R6 +
//  (a) pass1: xF unioned into the kvA buffer (wave-private, dead after each
//      tile's kv write) -> LDS 24->16 KB; __launch_bounds__(256,8) caps VGPR
//      at 64 -> 8 blocks/CU -> all 2048 blocks resident in ONE dispatch
//      round (no tail).  [R6: 68 VGPR/24KB -> ~6-7 blocks/CU, 2 rounds]
//  (b) pass2: block-staged fold. One block = (bc, 4 output rows); the 64
//      needed ao plane-rows (8 KB) staged coalesced (2x half8 per thread)
//      into LDS, then 16 x 2B LDS reads per pixel (2-way conflict = free).
//      [R6: 16 scalar 2B global gathers per pixel]
// Timed window includes a fixed ~45us harness fill of the 268MB workspace
// (confirmed: R1 478+44=522, R2 187.6+44+4=236, R4 387+44+8=439) — floor.
//
// MFMA layout identity (core trick, R5/R6): 16x16 MFMA C/D layout
// (lane=col+16*(row>>2), reg=row&3) == A-operand layout == B-operand layout:
//   K^T = Wk.X^T    -> A-frag of K      (for S^T = K.Q^T)
//   V   = X.Wv^T    -> A-frag of V^T    (for O^T = V^T.P^T)
//   Q^T = s.Wq.X^T  -> B-frag of Q^T
//   P^T = exp2(S^T) -> B-frag of P^T    (in-register)
// All fragments statically indexed (R4 lesson: dynamic reg-array indexing
// -> scratch lowering, 7x regression).

#define BATCH 2
#define CHAN 64
#define HWDIM 67
#define SEQ 256
#define DIM 16
#define NSEQ 2048            // BATCH*CHAN*16
#define PLANE 4096           // 64*64 elems per sequence
#define OUT_TOTAL (BATCH * CHAN * HWDIM * HWDIM)   // 574592
#define ATT_SCALE 0.70710678118654752f             // (DIM/HEADS)^-0.5
#define LOG2E 1.44269504088896340736f
#define HTILES 17            // ceil(67/4) output-row tiles per bc

typedef _Float16 half4 __attribute__((ext_vector_type(4)));
typedef _Float16 half8 __attribute__((ext_vector_type(8)));
typedef float float4v __attribute__((ext_vector_type(4)));

static __device__ __forceinline__ half4 pack4(float4v c) {
    half4 h;
    h[0] = (_Float16)c[0]; h[1] = (_Float16)c[1];
    h[2] = (_Float16)c[2]; h[3] = (_Float16)c[3];
    return h;
}

__global__ __launch_bounds__(256, 8) void ska_attn_pass1(
    const float* __restrict__ x,      // [B, C, 67, 67]
    const float* __restrict__ w,      // [48, 16]
    _Float16* __restrict__ ao)        // [NSEQ, 64, 64] workspace (f16)
{
    // unioned buffer: [0:4] holds the X-frag until tile t's projection, then
    // overwritten with [0:4]=K A-frag | [4:8]=V^T A-frag. 16 KB.
    __shared__ _Float16 buf[16][64][8];

    const int n  = blockIdx.x;
    const int p  = n & 15;
    const int bc = n >> 4;
    const int oi = p >> 2;
    const int oj = p & 3;

    const int s   = threadIdx.x;          // token id 0..255
    const int ph  = s >> 2;
    const int pw0 = (s & 3) * DIM;

    // stage this token's 16 features as f16 X-fragment (wave-private tiles:
    // kt = s>>4 lies in [4*wave, 4*wave+4))
    const float* xrow = x + ((size_t)bc * HWDIM + (ph + oi)) * HWDIM + pw0 + oj;
    const int kt = s >> 4, kk = s & 15;
#pragma unroll
    for (int dh = 0; dh < 4; ++dh) {
        half4 h;
#pragma unroll
        for (int r = 0; r < 4; ++r) h[r] = (_Float16)xrow[4 * dh + r];
        *(half4*)&buf[kt][kk + 16 * dh][0] = h;
    }

    const int wave = s >> 6;
    const int lane = s & 63;
    const int o = lane & 15;      // weight output row held by this lane
    const int g = lane >> 4;      // k-group

    // weight fragments straight from global (3 KB, L1-resident)
    const float4 wq4 = *(const float4*)(w + ( 0 + o) * DIM + 4 * g);
    const float4 wk4 = *(const float4*)(w + (16 + o) * DIM + 4 * g);
    const float4 wv4 = *(const float4*)(w + (32 + o) * DIM + 4 * g);
    half4 wqf, wkf, wvf;
    wqf[0] = (_Float16)(wq4.x * (ATT_SCALE * LOG2E));
    wqf[1] = (_Float16)(wq4.y * (ATT_SCALE * LOG2E));
    wqf[2] = (_Float16)(wq4.z * (ATT_SCALE * LOG2E));
    wqf[3] = (_Float16)(wq4.w * (ATT_SCALE * LOG2E));
    wkf[0] = (_Float16)wk4.x; wkf[1] = (_Float16)wk4.y;
    wkf[2] = (_Float16)wk4.z; wkf[3] = (_Float16)wk4.w;
    wvf[0] = (_Float16)wv4.x; wvf[1] = (_Float16)wv4.y;
    wvf[2] = (_Float16)wv4.z; wvf[3] = (_Float16)wv4.w;

    const float4v zf = (float4v){0.f, 0.f, 0.f, 0.f};

    // projection: wave w handles tiles 4w..4w+3 (the tiles it staged — no
    // barrier needed; xF portion of buf[t] is dead after kv write of tile t).
    half4 qfr[4];
#pragma unroll
    for (int u = 0; u < 4; ++u) {
        const int t = 4 * wave + u;
        const half4 xf = *(const half4*)&buf[t][lane][0];
        const half4 kf = pack4(__builtin_amdgcn_mfma_f32_16x16x16f16(wkf, xf, zf, 0, 0, 0));
        const half4 vf = pack4(__builtin_amdgcn_mfma_f32_16x16x16f16(xf, wvf, zf, 0, 0, 0));
        half8 kv;
        kv[0] = kf[0]; kv[1] = kf[1]; kv[2] = kf[2]; kv[3] = kf[3];
        kv[4] = vf[0]; kv[5] = vf[1]; kv[6] = vf[2]; kv[7] = vf[3];
        *(half8*)&buf[t][lane][0] = kv;
        qfr[u] = pack4(__builtin_amdgcn_mfma_f32_16x16x16f16(wqf, xf, zf, 0, 0, 0));
    }
    __syncthreads();   // kv frags ready (the only barrier)

    float4v oacc[4];
    float lpart[4];
#pragma unroll
    for (int j = 0; j < 4; ++j) {
        oacc[j] = zf;
        lpart[j] = 0.f;
    }

    // main loop: one ds_read_b128 per k-tile, rest pure register MFMA + exp2
#pragma unroll 4
    for (int t = 0; t < 16; ++t) {
        const half8 kv = *(const half8*)&buf[t][lane][0];
        half4 kf, vf;
        kf[0] = kv[0]; kf[1] = kv[1]; kf[2] = kv[2]; kf[3] = kv[3];
        vf[0] = kv[4]; vf[1] = kv[5]; vf[2] = kv[6]; vf[3] = kv[7];
#pragma unroll
        for (int j = 0; j < 4; ++j) {
            float4v sfr = __builtin_amdgcn_mfma_f32_16x16x16f16(kf, qfr[j], zf, 0, 0, 0);
            const float p0 = __builtin_amdgcn_exp2f(sfr[0]);
            const float p1 = __builtin_amdgcn_exp2f(sfr[1]);
            const float p2 = __builtin_amdgcn_exp2f(sfr[2]);
            const float p3 = __builtin_amdgcn_exp2f(sfr[3]);
            lpart[j] += (p0 + p1) + (p2 + p3);
            half4 pb;
            pb[0] = (_Float16)p0; pb[1] = (_Float16)p1;
            pb[2] = (_Float16)p2; pb[3] = (_Float16)p3;
            oacc[j] = __builtin_amdgcn_mfma_f32_16x16x16f16(vf, pb, oacc[j], 0, 0, 0);
        }
    }

    // softmax denom: sum lane groups {qq, qq+16, qq+32, qq+48}; store O^T frag
#pragma unroll
    for (int j = 0; j < 4; ++j) {
        float lj = lpart[j];
        lj += __shfl_xor(lj, 16, 64);
        lj += __shfl_xor(lj, 32, 64);
        const float rl = 1.f / lj;
        const int query = (4 * wave + j) * 16 + (lane & 15);
        half4 hv;
        hv[0] = (_Float16)(oacc[j][0] * rl);
        hv[1] = (_Float16)(oacc[j][1] * rl);
        hv[2] = (_Float16)(oacc[j][2] * rl);
        hv[3] = (_Float16)(oacc[j][3] * rl);
        *(half4*)(ao + (size_t)n * PLANE + query * DIM + 4 * g) = hv;
    }
}

// pass 2: block = (bc, 4 output rows). Stage the 16 planes x 4 rows of ao
// this block needs (8 KB) with coalesced 16B loads, then each pixel sums 16
// LDS halves. sA[pl][hh] holds ao[bc*16+pl][h0+hh - (pl>>2)][0:64] (0 if OOB).
__global__ __launch_bounds__(256) void ska_fold_pass2(
    const _Float16* __restrict__ ao,  // [NSEQ, 64, 64] f16
    float* __restrict__ out)          // [B, C, 67, 67]
{
    __shared__ _Float16 sA[16][4][64];   // 8 KB

    const int blk = blockIdx.x;
    const int h0  = (blk % HTILES) * 4;
    const int bc  = blk / HTILES;
    const int tid = threadIdx.x;

    // stage: 4096 halves, 16 per thread as 2x half8
    {
        const int pl = tid >> 4;           // plane 0..15
        const int hh = (tid >> 2) & 3;     // local row 0..3
        const int pw = (tid & 3) * 16;     // col base 0/16/32/48
        const int i  = pl >> 2;
        const int prow = h0 + hh - i;      // source plane row
        half8 v0, v1;
        if (prow >= 0 && prow < 64) {
            const _Float16* src = ao + ((size_t)(bc * 16 + pl)) * PLANE + prow * 64 + pw;
            v0 = *(const half8*)src;
            v1 = *(const half8*)(src + 8);
        } else {
            const half8 z = (half8)(_Float16)0.f;
            v0 = z; v1 = z;
        }
        *(half8*)&sA[pl][hh][pw]     = v0;
        *(half8*)&sA[pl][hh][pw + 8] = v1;
    }
    __syncthreads();

    for (int px = tid; px < 4 * HWDIM; px += 256) {
        const int hh = px / HWDIM;
        const int ww = px % HWDIM;
        const int h  = h0 + hh;
        if (h >= HWDIM) continue;
        float acc = 0.f;
#pragma unroll
        for (int i = 0; i < 4; ++i) {
#pragma unroll
            for (int j = 0; j < 4; ++j) {
                const int pw = ww - j;
                if (pw < 0 || pw >= 64) continue;
                acc += (float)sA[i * 4 + j][hh][pw];
            }
        }
        out[((size_t)bc * HWDIM + h) * HWDIM + ww] = acc;
    }
}

// ---- fallback (atomic fold) if workspace is too small ----
__global__ __launch_bounds__(256) void ska_attn_atomic(
    const float* __restrict__ x, const float* __restrict__ w,
    float* __restrict__ out)
{
    __shared__ float sw[3 * DIM * DIM];
    __shared__ float sk[SEQ][DIM];
    __shared__ float sv[SEQ][DIM];

    const int n = blockIdx.x, p = n & 15, bc = n >> 4, oi = p >> 2, oj = p & 3;
    const int s = threadIdx.x, ph = s >> 2, pw0 = (s & 3) * DIM;

#pragma unroll
    for (int r = 0; r < 3; ++r) sw[r * 256 + s] = w[r * 256 + s];

    const float* xrow = x + ((size_t)bc * HWDIM + (ph + oi)) * HWDIM + pw0 + oj;
    float xr[DIM];
#pragma unroll
    for (int d = 0; d < DIM; ++d) xr[d] = xrow[d];
    __syncthreads();

    float q[DIM];
#pragma unroll
    for (int o = 0; o < DIM; ++o) {
        float aq = 0.f, ak = 0.f, av = 0.f;
#pragma unroll
        for (int d = 0; d < DIM; ++d) {
            aq += xr[d] * sw[o * DIM + d];
            ak += xr[d] * sw[(DIM + o) * DIM + d];
            av += xr[d] * sw[(2 * DIM + o) * DIM + d];
        }
        q[o] = aq * ATT_SCALE; sk[s][o] = ak; sv[s][o] = av;
    }
    __syncthreads();

    float l = 0.f, acc[DIM];
#pragma unroll
    for (int d = 0; d < DIM; ++d) acc[d] = 0.f;
    for (int t = 0; t < SEQ; ++t) {
        float sc = 0.f;
#pragma unroll
        for (int d = 0; d < DIM; ++d) sc += q[d] * sk[t][d];
        const float pe = __expf(sc);
        l += pe;
#pragma unroll
        for (int d = 0; d < DIM; ++d) acc[d] += pe * sv[t][d];
    }
    const float rl = 1.f / l;
    float* obase = out + ((size_t)bc * HWDIM + (ph + oi)) * HWDIM + pw0 + oj;
#pragma unroll
    for (int d = 0; d < DIM; ++d) atomicAdd(&obase[d], acc[d] * rl);
}

extern "C" void kernel_launch(void* const* d_in, const int* in_sizes, int n_in,
                              void* d_out, int out_size, void* d_ws, size_t ws_size,
                              hipStream_t stream) {
    const float* x = (const float*)d_in[0];
    const float* w = (const float*)d_in[1];
    float* out = (float*)d_out;

    const size_t need = (size_t)NSEQ * PLANE * sizeof(_Float16);   // 16.8 MB
    if (ws_size >= need) {
        _Float16* ao = (_Float16*)d_ws;
        ska_attn_pass1<<<NSEQ, 256, 0, stream>>>(x, w, ao);
        ska_fold_pass2<<<BATCH * CHAN * HTILES, 256, 0, stream>>>(ao, out);
    } else {
        (void)hipMemsetAsync(out, 0, (size_t)out_size * sizeof(float), stream);
        ska_attn_atomic<<<NSEQ, 256, 0, stream>>>(x, w, out);
    }
}

// Round 8
// 86.881 us; speedup vs baseline: 5.0538x; 1.0228x over previous
//
#include <hip/hip_runtime.h>

// SlidingKernelAttention: unfold(k=4,s=1) -> per-(b,c,patch-offset) attention
// over seq=256 tokens of dim=16 -> overlap-add fold.
// B=2, C=64, H=W=67, Ho=Wo=64, N = B*C*16 = 2048 independent sequences.
//
// R8 = R7 with all f16 vector construction done via v_cvt_pkrtz pairs +
// bit_cast / shufflevector (register aliasing, ZERO VALU) instead of
// element-wise half inserts/extracts. R3's profile showed ~70 VALU instr
// per main-loop iteration (VALUBusy 60% x 52us = 146 cyc/iter) vs ~11
// algorithmic — the excess was 16-bit sub-register insert/extract ops from
// element-wise half4/half8 writes. This was the real pass1 bottleneck
// (pass1 ~40us of the 45us controllable budget; fill of d_ws by the
// harness is a fixed ~43.4us floor in the timed window).
//
// MFMA layout identity (R5-R7): 16x16 MFMA C/D layout == A-operand layout
// == B-operand layout, so projection MFMA results ARE attention operands:
//   K^T = Wk.X^T    -> A-frag of K      (for S^T = K.Q^T)
//   V   = X.Wv^T    -> A-frag of V^T    (for O^T = V^T.P^T)
//   Q^T = s.Wq.X^T  -> B-frag of Q^T
//   P^T = exp2(S^T) -> B-frag of P^T    (in-register)
// All fragments statically indexed (R4 lesson: dynamic reg-array indexing
// -> scratch lowering, 7x regression).

#define BATCH 2
#define CHAN 64
#define HWDIM 67
#define SEQ 256
#define DIM 16
#define NSEQ 2048            // BATCH*CHAN*16
#define PLANE 4096           // 64*64 elems per sequence
#define OUT_TOTAL (BATCH * CHAN * HWDIM * HWDIM)   // 574592
#define ATT_SCALE 0.70710678118654752f             // (DIM/HEADS)^-0.5
#define LOG2E 1.44269504088896340736f
#define HTILES 17            // ceil(67/4) output-row tiles per bc

typedef _Float16 half4 __attribute__((ext_vector_type(4)));
typedef _Float16 half8 __attribute__((ext_vector_type(8)));
typedef float float4v __attribute__((ext_vector_type(4)));
typedef __fp16 fp16x2 __attribute__((ext_vector_type(2)));
typedef unsigned int uint2v __attribute__((ext_vector_type(2)));

// 2x v_cvt_pkrtz + register-pair aliasing: zero insert/extract VALU.
static __device__ __forceinline__ half4 mk_half4(float a, float b, float c, float d) {
    fp16x2 lo = __builtin_amdgcn_cvt_pkrtz(a, b);
    fp16x2 hi = __builtin_amdgcn_cvt_pkrtz(c, d);
    uint2v u;
    u[0] = __builtin_bit_cast(unsigned int, lo);
    u[1] = __builtin_bit_cast(unsigned int, hi);
    return __builtin_bit_cast(half4, u);
}

static __device__ __forceinline__ half4 pack4(float4v c) {
    return mk_half4(c[0], c[1], c[2], c[3]);
}

__global__ __launch_bounds__(256, 8) void ska_attn_pass1(
    const float* __restrict__ x,      // [B, C, 67, 67]
    const float* __restrict__ w,      // [48, 16]
    _Float16* __restrict__ ao)        // [NSEQ, 64, 64] workspace (f16)
{
    // unioned buffer: [0:4] holds the X-frag until tile t's projection, then
    // overwritten with [0:4]=K A-frag | [4:8]=V^T A-frag. 16 KB.
    __shared__ __align__(16) _Float16 buf[16][64][8];

    const int n  = blockIdx.x;
    const int p  = n & 15;
    const int bc = n >> 4;
    const int oi = p >> 2;
    const int oj = p & 3;

    const int s   = threadIdx.x;          // token id 0..255
    const int ph  = s >> 2;
    const int pw0 = (s & 3) * DIM;

    // stage this token's 16 features as f16 X-fragment (wave-private tiles:
    // kt = s>>4 lies in [4*wave, 4*wave+4))
    const float* xrow = x + ((size_t)bc * HWDIM + (ph + oi)) * HWDIM + pw0 + oj;
    const int kt = s >> 4, kk = s & 15;
#pragma unroll
    for (int dh = 0; dh < 4; ++dh) {
        const half4 h = mk_half4(xrow[4 * dh + 0], xrow[4 * dh + 1],
                                 xrow[4 * dh + 2], xrow[4 * dh + 3]);
        *(half4*)&buf[kt][kk + 16 * dh][0] = h;
    }

    const int wave = s >> 6;
    const int lane = s & 63;
    const int o = lane & 15;      // weight output row held by this lane
    const int g = lane >> 4;      // k-group

    // weight fragments straight from global (3 KB, L1-resident)
    const float4 wq4 = *(const float4*)(w + ( 0 + o) * DIM + 4 * g);
    const float4 wk4 = *(const float4*)(w + (16 + o) * DIM + 4 * g);
    const float4 wv4 = *(const float4*)(w + (32 + o) * DIM + 4 * g);
    const half4 wqf = mk_half4(wq4.x * (ATT_SCALE * LOG2E), wq4.y * (ATT_SCALE * LOG2E),
                               wq4.z * (ATT_SCALE * LOG2E), wq4.w * (ATT_SCALE * LOG2E));
    const half4 wkf = mk_half4(wk4.x, wk4.y, wk4.z, wk4.w);
    const half4 wvf = mk_half4(wv4.x, wv4.y, wv4.z, wv4.w);

    const float4v zf = (float4v){0.f, 0.f, 0.f, 0.f};

    // projection: wave w handles tiles 4w..4w+3 (the tiles it staged — no
    // barrier needed; xF portion of buf[t] is dead after kv write of tile t).
    half4 qfr[4];
#pragma unroll
    for (int u = 0; u < 4; ++u) {
        const int t = 4 * wave + u;
        const half4 xf = *(const half4*)&buf[t][lane][0];
        const half4 kf = pack4(__builtin_amdgcn_mfma_f32_16x16x16f16(wkf, xf, zf, 0, 0, 0));
        const half4 vf = pack4(__builtin_amdgcn_mfma_f32_16x16x16f16(xf, wvf, zf, 0, 0, 0));
        const half8 kv = __builtin_shufflevector(kf, vf, 0, 1, 2, 3, 4, 5, 6, 7);
        *(half8*)&buf[t][lane][0] = kv;
        qfr[u] = pack4(__builtin_amdgcn_mfma_f32_16x16x16f16(wqf, xf, zf, 0, 0, 0));
    }
    __syncthreads();   // kv frags ready (the only barrier)

    float4v oacc[4];
    float lpart[4];
#pragma unroll
    for (int j = 0; j < 4; ++j) {
        oacc[j] = zf;
        lpart[j] = 0.f;
    }

    // main loop: one ds_read_b128 per k-tile; operand splits are register
    // aliases (shufflevector), P-pack is 2x cvt_pkrtz — ~11 VALU per (t,j).
#pragma unroll 4
    for (int t = 0; t < 16; ++t) {
        const half8 kv = *(const half8*)&buf[t][lane][0];
        const half4 kf = __builtin_shufflevector(kv, kv, 0, 1, 2, 3);
        const half4 vf = __builtin_shufflevector(kv, kv, 4, 5, 6, 7);
#pragma unroll
        for (int j = 0; j < 4; ++j) {
            float4v sfr = __builtin_amdgcn_mfma_f32_16x16x16f16(kf, qfr[j], zf, 0, 0, 0);
            const float p0 = __builtin_amdgcn_exp2f(sfr[0]);
            const float p1 = __builtin_amdgcn_exp2f(sfr[1]);
            const float p2 = __builtin_amdgcn_exp2f(sfr[2]);
            const float p3 = __builtin_amdgcn_exp2f(sfr[3]);
            lpart[j] += (p0 + p1) + (p2 + p3);
            const half4 pb = mk_half4(p0, p1, p2, p3);
            oacc[j] = __builtin_amdgcn_mfma_f32_16x16x16f16(vf, pb, oacc[j], 0, 0, 0);
        }
    }

    // softmax denom: sum lane groups {qq, qq+16, qq+32, qq+48}; store O^T frag
#pragma unroll
    for (int j = 0; j < 4; ++j) {
        float lj = lpart[j];
        lj += __shfl_xor(lj, 16, 64);
        lj += __shfl_xor(lj, 32, 64);
        const float rl = 1.f / lj;
        const int query = (4 * wave + j) * 16 + (lane & 15);
        const half4 hv = mk_half4(oacc[j][0] * rl, oacc[j][1] * rl,
                                  oacc[j][2] * rl, oacc[j][3] * rl);
        *(half4*)(ao + (size_t)n * PLANE + query * DIM + 4 * g) = hv;
    }
}

// pass 2: block = (bc, 4 output rows). Stage the 16 planes x 4 rows of ao
// this block needs (8 KB) with coalesced 16B loads, then each pixel sums 16
// LDS halves. sA[pl][hh] holds ao[bc*16+pl][h0+hh - (pl>>2)][0:64] (0 if OOB).
__global__ __launch_bounds__(256) void ska_fold_pass2(
    const _Float16* __restrict__ ao,  // [NSEQ, 64, 64] f16
    float* __restrict__ out)          // [B, C, 67, 67]
{
    __shared__ __align__(16) _Float16 sA[16][4][64];   // 8 KB

    const int blk = blockIdx.x;
    const int h0  = (blk % HTILES) * 4;
    const int bc  = blk / HTILES;
    const int tid = threadIdx.x;

    // stage: 4096 halves, 16 per thread as 2x half8
    {
        const int pl = tid >> 4;           // plane 0..15
        const int hh = (tid >> 2) & 3;     // local row 0..3
        const int pw = (tid & 3) * 16;     // col base 0/16/32/48
        const int i  = pl >> 2;
        const int prow = h0 + hh - i;      // source plane row
        half8 v0, v1;
        if (prow >= 0 && prow < 64) {
            const _Float16* src = ao + ((size_t)(bc * 16 + pl)) * PLANE + prow * 64 + pw;
            v0 = *(const half8*)src;
            v1 = *(const half8*)(src + 8);
        } else {
            const half8 z = (half8)(_Float16)0.f;
            v0 = z; v1 = z;
        }
        *(half8*)&sA[pl][hh][pw]     = v0;
        *(half8*)&sA[pl][hh][pw + 8] = v1;
    }
    __syncthreads();

    for (int px = tid; px < 4 * HWDIM; px += 256) {
        const int hh = px / HWDIM;
        const int ww = px % HWDIM;
        const int h  = h0 + hh;
        if (h >= HWDIM) continue;
        float acc = 0.f;
#pragma unroll
        for (int i = 0; i < 4; ++i) {
#pragma unroll
            for (int j = 0; j < 4; ++j) {
                const int pw = ww - j;
                if (pw < 0 || pw >= 64) continue;
                acc += (float)sA[i * 4 + j][hh][pw];
            }
        }
        out[((size_t)bc * HWDIM + h) * HWDIM + ww] = acc;
    }
}

// ---- fallback (atomic fold) if workspace is too small ----
__global__ __launch_bounds__(256) void ska_attn_atomic(
    const float* __restrict__ x, const float* __restrict__ w,
    float* __restrict__ out)
{
    __shared__ float sw[3 * DIM * DIM];
    __shared__ float sk[SEQ][DIM];
    __shared__ float sv[SEQ][DIM];

    const int n = blockIdx.x, p = n & 15, bc = n >> 4, oi = p >> 2, oj = p & 3;
    const int s = threadIdx.x, ph = s >> 2, pw0 = (s & 3) * DIM;

#pragma unroll
    for (int r = 0; r < 3; ++r) sw[r * 256 + s] = w[r * 256 + s];

    const float* xrow = x + ((size_t)bc * HWDIM + (ph + oi)) * HWDIM + pw0 + oj;
    float xr[DIM];
#pragma unroll
    for (int d = 0; d < DIM; ++d) xr[d] = xrow[d];
    __syncthreads();

    float q[DIM];
#pragma unroll
    for (int o = 0; o < DIM; ++o) {
        float aq = 0.f, ak = 0.f, av = 0.f;
#pragma unroll
        for (int d = 0; d < DIM; ++d) {
            aq += xr[d] * sw[o * DIM + d];
            ak += xr[d] * sw[(DIM + o) * DIM + d];
            av += xr[d] * sw[(2 * DIM + o) * DIM + d];
        }
        q[o] = aq * ATT_SCALE; sk[s][o] = ak; sv[s][o] = av;
    }
    __syncthreads();

    float l = 0.f, acc[DIM];
#pragma unroll
    for (int d = 0; d < DIM; ++d) acc[d] = 0.f;
    for (int t = 0; t < SEQ; ++t) {
        float sc = 0.f;
#pragma unroll
        for (int d = 0; d < DIM; ++d) sc += q[d] * sk[t][d];
        const float pe = __expf(sc);
        l += pe;
#pragma unroll
        for (int d = 0; d < DIM; ++d) acc[d] += pe * sv[t][d];
    }
    const float rl = 1.f / l;
    float* obase = out + ((size_t)bc * HWDIM + (ph + oi)) * HWDIM + pw0 + oj;
#pragma unroll
    for (int d = 0; d < DIM; ++d) atomicAdd(&obase[d], acc[d] * rl);
}

extern "C" void kernel_launch(void* const* d_in, const int* in_sizes, int n_in,
                              void* d_out, int out_size, void* d_ws, size_t ws_size,
                              hipStream_t stream) {
    const float* x = (const float*)d_in[0];
    const float* w = (const float*)d_in[1];
    float* out = (float*)d_out;

    const size_t need = (size_t)NSEQ * PLANE * sizeof(_Float16);   // 16.8 MB
    if (ws_size >= need) {
        _Float16* ao = (_Float16*)d_ws;
        ska_attn_pass1<<<NSEQ, 256, 0, stream>>>(x, w, ao);
        ska_fold_pass2<<<BATCH * CHAN * HTILES, 256, 0, stream>>>(ao, out);
    } else {
        (void)hipMemsetAsync(out, 0, (size_t)out_size * sizeof(float), stream);
        ska_attn_atomic<<<NSEQ, 256, 0, stream>>>(x, w, out);
    }
}

// Round 9
// 85.149 us; speedup vs baseline: 5.1567x; 1.0203x over previous
//
#include <hip/hip_runtime.h>

// SlidingKernelAttention: unfold(k=4,s=1) -> per-(b,c,patch-offset) attention
// over seq=256 tokens of dim=16 -> overlap-add fold.
// B=2, C=64, H=W=67, Ho=Wo=64, N = B*C*16 = 2048 independent sequences.
//
// R9 = R8 with pass1 at 512 threads / 2 sequences per block (grid 2048->1024).
// R8's post-mortem: cutting ~50 VALU/iter changed nothing (-2us) => pass1
// is NOT issue-bound; pipe arithmetic says ~10-14us achievable vs ~38us
// measured. Occupancy counter collapsed as kernels shortened (R1 37% @478us
// -> R3 25% @52us) => short-lived 256-thr/16KB WGs never reach steady-state
// residency (launch/ramp granularity). Fatter, longer-lived WGs amortize
// allocation and extend the overlap plateau. Loop body identical to R8.
//
// MFMA layout identity (R5-R8): 16x16 MFMA C/D layout == A-operand layout
// == B-operand layout, so projection MFMA results ARE attention operands:
//   K^T = Wk.X^T    -> A-frag of K      (for S^T = K.Q^T)
//   V   = X.Wv^T    -> A-frag of V^T    (for O^T = V^T.P^T)
//   Q^T = s.Wq.X^T  -> B-frag of Q^T
//   P^T = exp2(S^T) -> B-frag of P^T    (in-register)
// All fragments statically indexed (R4 lesson: dynamic reg-array indexing
// -> scratch lowering). f16 vectors built via v_cvt_pkrtz + bit_cast /
// shufflevector only (R8: no sub-register insert/extract).
// Timed window includes a fixed ~43.4us harness fill of the 268MB d_ws.

#define BATCH 2
#define CHAN 64
#define HWDIM 67
#define SEQ 256
#define DIM 16
#define NSEQ 2048            // BATCH*CHAN*16
#define PLANE 4096           // 64*64 elems per sequence
#define OUT_TOTAL (BATCH * CHAN * HWDIM * HWDIM)   // 574592
#define ATT_SCALE 0.70710678118654752f             // (DIM/HEADS)^-0.5
#define LOG2E 1.44269504088896340736f
#define HTILES 17            // ceil(67/4) output-row tiles per bc

typedef _Float16 half4 __attribute__((ext_vector_type(4)));
typedef _Float16 half8 __attribute__((ext_vector_type(8)));
typedef float float4v __attribute__((ext_vector_type(4)));
typedef __fp16 fp16x2 __attribute__((ext_vector_type(2)));
typedef unsigned int uint2v __attribute__((ext_vector_type(2)));

// 2x v_cvt_pkrtz + register-pair aliasing: zero insert/extract VALU.
static __device__ __forceinline__ half4 mk_half4(float a, float b, float c, float d) {
    fp16x2 lo = __builtin_amdgcn_cvt_pkrtz(a, b);
    fp16x2 hi = __builtin_amdgcn_cvt_pkrtz(c, d);
    uint2v u;
    u[0] = __builtin_bit_cast(unsigned int, lo);
    u[1] = __builtin_bit_cast(unsigned int, hi);
    return __builtin_bit_cast(half4, u);
}

static __device__ __forceinline__ half4 pack4(float4v c) {
    return mk_half4(c[0], c[1], c[2], c[3]);
}

__global__ __launch_bounds__(512, 4) void ska_attn_pass1(
    const float* __restrict__ x,      // [B, C, 67, 67]
    const float* __restrict__ w,      // [48, 16]
    _Float16* __restrict__ ao)        // [NSEQ, 64, 64] workspace (f16)
{
    // two sequences per block; per-sequence unioned buffer: [0:4] holds the
    // X-frag until tile t's projection, then [0:4]=K A-frag | [4:8]=V^T
    // A-frag. 2 x 16 KB.
    __shared__ __align__(16) _Float16 buf[2][16][64][8];

    const int half_id = threadIdx.x >> 8;           // which of the 2 sequences
    const int n  = blockIdx.x * 2 + half_id;
    const int p  = n & 15;
    const int bc = n >> 4;
    const int oi = p >> 2;
    const int oj = p & 3;

    const int s   = threadIdx.x & 255;    // token id 0..255 within sequence
    const int ph  = s >> 2;
    const int pw0 = (s & 3) * DIM;

    // stage this token's 16 features as f16 X-fragment (wave-private tiles:
    // kt = s>>4 lies in [4*wave, 4*wave+4))
    const float* xrow = x + ((size_t)bc * HWDIM + (ph + oi)) * HWDIM + pw0 + oj;
    const int kt = s >> 4, kk = s & 15;
#pragma unroll
    for (int dh = 0; dh < 4; ++dh) {
        const half4 h = mk_half4(xrow[4 * dh + 0], xrow[4 * dh + 1],
                                 xrow[4 * dh + 2], xrow[4 * dh + 3]);
        *(half4*)&buf[half_id][kt][kk + 16 * dh][0] = h;
    }

    const int wave = (threadIdx.x >> 6) & 3;   // wave within this sequence
    const int lane = threadIdx.x & 63;
    const int o = lane & 15;      // weight output row held by this lane
    const int g = lane >> 4;      // k-group

    // weight fragments straight from global (3 KB, L1-resident)
    const float4 wq4 = *(const float4*)(w + ( 0 + o) * DIM + 4 * g);
    const float4 wk4 = *(const float4*)(w + (16 + o) * DIM + 4 * g);
    const float4 wv4 = *(const float4*)(w + (32 + o) * DIM + 4 * g);
    const half4 wqf = mk_half4(wq4.x * (ATT_SCALE * LOG2E), wq4.y * (ATT_SCALE * LOG2E),
                               wq4.z * (ATT_SCALE * LOG2E), wq4.w * (ATT_SCALE * LOG2E));
    const half4 wkf = mk_half4(wk4.x, wk4.y, wk4.z, wk4.w);
    const half4 wvf = mk_half4(wv4.x, wv4.y, wv4.z, wv4.w);

    const float4v zf = (float4v){0.f, 0.f, 0.f, 0.f};

    // projection: wave w handles tiles 4w..4w+3 (the tiles it staged — no
    // barrier needed; xF portion of buf[t] is dead after kv write of tile t).
    half4 qfr[4];
#pragma unroll
    for (int u = 0; u < 4; ++u) {
        const int t = 4 * wave + u;
        const half4 xf = *(const half4*)&buf[half_id][t][lane][0];
        const half4 kf = pack4(__builtin_amdgcn_mfma_f32_16x16x16f16(wkf, xf, zf, 0, 0, 0));
        const half4 vf = pack4(__builtin_amdgcn_mfma_f32_16x16x16f16(xf, wvf, zf, 0, 0, 0));
        const half8 kv = __builtin_shufflevector(kf, vf, 0, 1, 2, 3, 4, 5, 6, 7);
        *(half8*)&buf[half_id][t][lane][0] = kv;
        qfr[u] = pack4(__builtin_amdgcn_mfma_f32_16x16x16f16(wqf, xf, zf, 0, 0, 0));
    }
    __syncthreads();   // kv frags ready (the only barrier; syncs both halves)

    float4v oacc[4];
    float lpart[4];
#pragma unroll
    for (int j = 0; j < 4; ++j) {
        oacc[j] = zf;
        lpart[j] = 0.f;
    }

    // main loop: one ds_read_b128 per k-tile; operand splits are register
    // aliases (shufflevector), P-pack is 2x cvt_pkrtz.
#pragma unroll 4
    for (int t = 0; t < 16; ++t) {
        const half8 kv = *(const half8*)&buf[half_id][t][lane][0];
        const half4 kf = __builtin_shufflevector(kv, kv, 0, 1, 2, 3);
        const half4 vf = __builtin_shufflevector(kv, kv, 4, 5, 6, 7);
#pragma unroll
        for (int j = 0; j < 4; ++j) {
            float4v sfr = __builtin_amdgcn_mfma_f32_16x16x16f16(kf, qfr[j], zf, 0, 0, 0);
            const float p0 = __builtin_amdgcn_exp2f(sfr[0]);
            const float p1 = __builtin_amdgcn_exp2f(sfr[1]);
            const float p2 = __builtin_amdgcn_exp2f(sfr[2]);
            const float p3 = __builtin_amdgcn_exp2f(sfr[3]);
            lpart[j] += (p0 + p1) + (p2 + p3);
            const half4 pb = mk_half4(p0, p1, p2, p3);
            oacc[j] = __builtin_amdgcn_mfma_f32_16x16x16f16(vf, pb, oacc[j], 0, 0, 0);
        }
    }

    // softmax denom: sum lane groups {qq, qq+16, qq+32, qq+48}; store O^T frag
#pragma unroll
    for (int j = 0; j < 4; ++j) {
        float lj = lpart[j];
        lj += __shfl_xor(lj, 16, 64);
        lj += __shfl_xor(lj, 32, 64);
        const float rl = 1.f / lj;
        const int query = (4 * wave + j) * 16 + (lane & 15);
        const half4 hv = mk_half4(oacc[j][0] * rl, oacc[j][1] * rl,
                                  oacc[j][2] * rl, oacc[j][3] * rl);
        *(half4*)(ao + (size_t)n * PLANE + query * DIM + 4 * g) = hv;
    }
}

// pass 2: block = (bc, 4 output rows). Stage the 16 planes x 4 rows of ao
// this block needs (8 KB) with coalesced 16B loads, then each pixel sums 16
// LDS halves. sA[pl][hh] holds ao[bc*16+pl][h0+hh - (pl>>2)][0:64] (0 if OOB).
__global__ __launch_bounds__(256) void ska_fold_pass2(
    const _Float16* __restrict__ ao,  // [NSEQ, 64, 64] f16
    float* __restrict__ out)          // [B, C, 67, 67]
{
    __shared__ __align__(16) _Float16 sA[16][4][64];   // 8 KB

    const int blk = blockIdx.x;
    const int h0  = (blk % HTILES) * 4;
    const int bc  = blk / HTILES;
    const int tid = threadIdx.x;

    // stage: 4096 halves, 16 per thread as 2x half8
    {
        const int pl = tid >> 4;           // plane 0..15
        const int hh = (tid >> 2) & 3;     // local row 0..3
        const int pw = (tid & 3) * 16;     // col base 0/16/32/48
        const int i  = pl >> 2;
        const int prow = h0 + hh - i;      // source plane row
        half8 v0, v1;
        if (prow >= 0 && prow < 64) {
            const _Float16* src = ao + ((size_t)(bc * 16 + pl)) * PLANE + prow * 64 + pw;
            v0 = *(const half8*)src;
            v1 = *(const half8*)(src + 8);
        } else {
            const half8 z = (half8)(_Float16)0.f;
            v0 = z; v1 = z;
        }
        *(half8*)&sA[pl][hh][pw]     = v0;
        *(half8*)&sA[pl][hh][pw + 8] = v1;
    }
    __syncthreads();

    for (int px = tid; px < 4 * HWDIM; px += 256) {
        const int hh = px / HWDIM;
        const int ww = px % HWDIM;
        const int h  = h0 + hh;
        if (h >= HWDIM) continue;
        float acc = 0.f;
#pragma unroll
        for (int i = 0; i < 4; ++i) {
#pragma unroll
            for (int j = 0; j < 4; ++j) {
                const int pw = ww - j;
                if (pw < 0 || pw >= 64) continue;
                acc += (float)sA[i * 4 + j][hh][pw];
            }
        }
        out[((size_t)bc * HWDIM + h) * HWDIM + ww] = acc;
    }
}

// ---- fallback (atomic fold) if workspace is too small ----
__global__ __launch_bounds__(256) void ska_attn_atomic(
    const float* __restrict__ x, const float* __restrict__ w,
    float* __restrict__ out)
{
    __shared__ float sw[3 * DIM * DIM];
    __shared__ float sk[SEQ][DIM];
    __shared__ float sv[SEQ][DIM];

    const int n = blockIdx.x, p = n & 15, bc = n >> 4, oi = p >> 2, oj = p & 3;
    const int s = threadIdx.x, ph = s >> 2, pw0 = (s & 3) * DIM;

#pragma unroll
    for (int r = 0; r < 3; ++r) sw[r * 256 + s] = w[r * 256 + s];

    const float* xrow = x + ((size_t)bc * HWDIM + (ph + oi)) * HWDIM + pw0 + oj;
    float xr[DIM];
#pragma unroll
    for (int d = 0; d < DIM; ++d) xr[d] = xrow[d];
    __syncthreads();

    float q[DIM];
#pragma unroll
    for (int o = 0; o < DIM; ++o) {
        float aq = 0.f, ak = 0.f, av = 0.f;
#pragma unroll
        for (int d = 0; d < DIM; ++d) {
            aq += xr[d] * sw[o * DIM + d];
            ak += xr[d] * sw[(DIM + o) * DIM + d];
            av += xr[d] * sw[(2 * DIM + o) * DIM + d];
        }
        q[o] = aq * ATT_SCALE; sk[s][o] = ak; sv[s][o] = av;
    }
    __syncthreads();

    float l = 0.f, acc[DIM];
#pragma unroll
    for (int d = 0; d < DIM; ++d) acc[d] = 0.f;
    for (int t = 0; t < SEQ; ++t) {
        float sc = 0.f;
#pragma unroll
        for (int d = 0; d < DIM; ++d) sc += q[d] * sk[t][d];
        const float pe = __expf(sc);
        l += pe;
#pragma unroll
        for (int d = 0; d < DIM; ++d) acc[d] += pe * sv[t][d];
    }
    const float rl = 1.f / l;
    float* obase = out + ((size_t)bc * HWDIM + (ph + oi)) * HWDIM + pw0 + oj;
#pragma unroll
    for (int d = 0; d < DIM; ++d) atomicAdd(&obase[d], acc[d] * rl);
}

extern "C" void kernel_launch(void* const* d_in, const int* in_sizes, int n_in,
                              void* d_out, int out_size, void* d_ws, size_t ws_size,
                              hipStream_t stream) {
    const float* x = (const float*)d_in[0];
    const float* w = (const float*)d_in[1];
    float* out = (float*)d_out;

    const size_t need = (size_t)NSEQ * PLANE * sizeof(_Float16);   // 16.8 MB
    if (ws_size >= need) {
        _Float16* ao = (_Float16*)d_ws;
        ska_attn_pass1<<<NSEQ / 2, 512, 0, stream>>>(x, w, ao);
        ska_fold_pass2<<<BATCH * CHAN * HTILES, 256, 0, stream>>>(ao, out);
    } else {
        (void)hipMemsetAsync(out, 0, (size_t)out_size * sizeof(float), stream);
        ska_attn_atomic<<<NSEQ, 256, 0, stream>>>(x, w, out);
    }
}